// Round 10
// baseline (274.952 us; speedup 1.0000x reference)
//
#include <hip/hip_runtime.h>
#include <hip/hip_bf16.h>

#define T_LEN 4096
#define BATCH 8
#define D_DIM 256
#define P_DIM 256
#define O_DIM 256
#define N3    768

typedef __bf16 bf16;
typedef __attribute__((ext_vector_type(8))) __bf16 bf16x8;
typedef __attribute__((ext_vector_type(4))) __bf16 bf16x4;
typedef __attribute__((ext_vector_type(4))) float f32x4;
typedef __attribute__((ext_vector_type(16))) float f32x16;

#define MFMA16(a, b, c) __builtin_amdgcn_mfma_f32_16x16x32_bf16(a, b, c, 0, 0, 0)
#define MFMA32(a, b, c) __builtin_amdgcn_mfma_f32_32x32x16_bf16(a, b, c, 0, 0, 0)

#define LDS_P 72  // P rows: 144B stride

// lgkm-only barrier: drains LDS ops but leaves global loads/stores in flight.
#define BARRIER_LGKM() __asm__ __volatile__("s_waitcnt lgkmcnt(0)\n\ts_barrier" ::: "memory")

// ---------------------------------------------------------------------------
// K0: fragment-major weight pack (proven), both weights in ONE dispatch.
// ---------------------------------------------------------------------------
__device__ __forceinline__ void wpack_body(
    const float* __restrict__ src, bf16* __restrict__ dst, int ncols, int g)
{
    const int lane = g & 63;
    const int idx = g >> 6;
    const int nt = idx & 3, kt = (idx >> 2) & 7, ch = idx >> 5;
    const int n = ch * 64 + nt * 16 + (lane & 15);
    const int kb = kt * 32 + (lane >> 4) * 8;
    bf16x8 pk;
    #pragma unroll
    for (int j = 0; j < 8; ++j) pk[j] = (bf16)src[(size_t)(kb + j) * ncols + n];
    *(bf16x8*)&dst[(size_t)g * 8] = pk;
}

__global__ __launch_bounds__(256) void wpack_all_kernel(
    const float* __restrict__ W_kqv, const float* __restrict__ W_out,
    bf16* __restrict__ wkp, bf16* __restrict__ wop)
{
    const int bid = blockIdx.x;
    if (bid < 96) {
        wpack_body(W_kqv, wkp, N3, bid * 256 + threadIdx.x);
    } else {
        wpack_body(W_out, wop, O_DIM, (bid - 96) * 256 + threadIdx.x);
    }
}

// ---------------------------------------------------------------------------
// K1 v8: qkv proj — DIRECT packed-weight loads + Tt vector stores.
//  - Isolation test (R5/R6 never separated): Wb staging costs 1 extra
//    barrier/ch + vmcnt(8) wait + GLD16 issue + 64 KB LDS. With stores
//    vectorized (R6's proven Tt paths), direct bb loads from wkp are L1/L2
//    resident (both co-resident blocks stream the SAME ch-tile) — drop the
//    staging machinery entirely. Barriers/ch 3->2, LDS 74->9 KB.
//  - bb loads + MFMA order + (bf16)((acc+bias)*scale) rounding identical to
//    R4/R6 -> bit-identical outputs.
// ---------------------------------------------------------------------------
__global__ __launch_bounds__(256) void qkv_proj_kernel(
    const float* __restrict__ query, const bf16* __restrict__ wkp,
    const float* __restrict__ b_kqv,
    bf16* __restrict__ qb, bf16* __restrict__ kpk, bf16* __restrict__ vpk)
{
    __shared__ __align__(16) bf16 Tt[64][72];     // 9 KB transpose tile
    const int m0 = blockIdx.x * 64;
    const int t0g = m0 >> 3;
    const int tid = threadIdx.x;
    const int lane = tid & 63, wave = tid >> 6, l15 = lane & 15, quad = lane >> 4;
    const int arow = wave * 16 + l15;

    bf16x8 af[8];
    {
        const float* qsrc = query + (size_t)(m0 + arow) * D_DIM + quad * 8;
        #pragma unroll
        for (int kt = 0; kt < 8; ++kt) {
            float4 f0 = *(const float4*)(qsrc + kt * 32);
            float4 f1 = *(const float4*)(qsrc + kt * 32 + 4);
            af[kt] = bf16x8{(bf16)f0.x, (bf16)f0.y, (bf16)f0.z, (bf16)f0.w,
                            (bf16)f1.x, (bf16)f1.y, (bf16)f1.z, (bf16)f1.w};
        }
    }

    for (int ch = 0; ch < 12; ++ch) {
        f32x4 acc[4];
        #pragma unroll
        for (int i = 0; i < 4; ++i)
            for (int r = 0; r < 4; ++r) acc[i][r] = 0.f;
        #pragma unroll
        for (int kt = 0; kt < 8; ++kt) {
            #pragma unroll
            for (int nt = 0; nt < 4; ++nt) {
                bf16x8 bb = *(const bf16x8*)&wkp[((((size_t)ch * 8 + kt) * 4 + nt) * 64 + lane) * 8];
                acc[nt] = MFMA16(af[kt], bb, acc[nt]);
            }
        }

        BARRIER_LGKM();   // Tt free (previous iter's readers retired)

        if (ch < 8) {
            // q/k: stage m-major (scaled q), bit-identical rounding
            const float scale = (ch < 4) ? 0.0625f : 1.0f;
            #pragma unroll
            for (int nt = 0; nt < 4; ++nt) {
                const int c = ch * 64 + nt * 16 + l15;
                const float bias = b_kqv[c];
                #pragma unroll
                for (int r = 0; r < 4; ++r)
                    Tt[wave * 16 + quad * 4 + r][nt * 16 + l15]
                        = (bf16)((acc[nt][r] + bias) * scale);
            }
            BARRIER_LGKM();   // Tt visible
            if (ch < 4) {
                #pragma unroll
                for (int uu = 0; uu < 2; ++uu) {
                    const int u = tid * 2 + uu;
                    const int row = u >> 3, cl = u & 7;
                    bf16x8 pk = *(const bf16x8*)&Tt[row][cl * 8];
                    const int m = m0 + row, t = m >> 3, bi = m & 7;
                    *(bf16x8*)&qb[((size_t)bi * T_LEN + t) * P_DIM + ch * 64 + cl * 8] = pk;
                }
            } else {
                #pragma unroll
                for (int uu = 0; uu < 2; ++uu) {
                    const int u = tid * 2 + uu;
                    const int cl = u >> 6, bi = (u >> 3) & 7, idx = u & 7;
                    const int row = idx * 8 + bi;
                    bf16x8 pk = *(const bf16x8*)&Tt[row][cl * 8];
                    const int t = t0g + idx;
                    const int st32 = t >> 5, n31 = t & 31;
                    const int c16 = (ch - 4) * 4 + (cl >> 1), halfk = cl & 1;
                    *(bf16x8*)&kpk[(size_t)((((bi * 128 + st32) * 16 + c16) * 64
                                             + halfk * 32 + n31) * 8)] = pk;
                }
            }
        } else {
            // V: stage c-major (fragment pack needs m-gather) — proven path
            #pragma unroll
            for (int nt = 0; nt < 4; ++nt) {
                const int c = ch * 64 + nt * 16 + l15;
                const float bias = b_kqv[c];
                #pragma unroll
                for (int r = 0; r < 4; ++r)
                    Tt[nt * 16 + l15][wave * 16 + quad * 4 + r] = (bf16)(acc[nt][r] + bias);
            }
            BARRIER_LGKM();   // Tt visible
            const int s64 = t0g >> 6, ks = (t0g >> 4) & 3, halfv = (t0g >> 3) & 1;
            #pragma unroll
            for (int uu = 0; uu < 2; ++uu) {
                const int u = tid * 2 + uu;
                const int cl = u >> 3, bi = u & 7;
                bf16x8 pk;
                #pragma unroll
                for (int j = 0; j < 8; ++j) pk[j] = Tt[cl][j * 8 + bi];
                const int cc = (ch - 8) * 64 + cl;
                const int ptG = cc >> 5, n31 = cc & 31;
                *(bf16x8*)&vpk[((((size_t)bi * 64 + s64) * 4 + ks) * 8 + ptG) * 512
                               + (size_t)(halfv * 32 + n31) * 8] = pk;
            }
        }
    }
}

// ---------------------------------------------------------------------------
// K2 v9 (kept from R9 — flash 171.1 µs verified): flash attention + fused
// out_proj; QK as two independent 8-MFMA chains (real -4 µs, no spills).
// ---------------------------------------------------------------------------
__global__ __launch_bounds__(256, 2) void flash_attn_kernel(
    const bf16* __restrict__ qb, const bf16* __restrict__ kpk,
    const bf16* __restrict__ vpk, const bf16* __restrict__ wop,
    const float* __restrict__ b_out, float* __restrict__ out)
{
    __shared__ __align__(16) bf16 Ps[2][64][LDS_P];   // 18.4 KB
    __shared__ float l_red[2][64];                    // [sh][row]
    __shared__ __align__(16) bf16 At[64][264];        // 33.8 KB

    const int bid = blockIdx.x;
    const int b = bid & 7;                 // bid%8 == XCD: 4 MB KV per XCD L2
    const int t0 = (bid >> 3) * 64;
    const int tid = threadIdx.x;
    const int lane = tid & 63, wave = tid >> 6;
    const int l31 = lane & 31, half = lane >> 5;
    const int rg = wave & 1, sh = wave >> 1;

    // Q A-frags (row=lane&31, k=half*8+j), rows rg*32..+32 — proven layout
    bf16x8 qf[16];
    {
        const bf16* qrow = qb + ((size_t)b * T_LEN + t0 + rg * 32 + l31) * P_DIM + half * 8;
        #pragma unroll
        for (int kt = 0; kt < 16; ++kt) qf[kt] = *(const bf16x8*)(qrow + kt * 16);
    }

    f32x16 acc_o[2][2];   // [t-tile][p-tile]
    float l_part[16];
    #pragma unroll
    for (int i = 0; i < 16; ++i) {
        acc_o[0][0][i] = 0.f; acc_o[0][1][i] = 0.f;
        acc_o[1][0][i] = 0.f; acc_o[1][1][i] = 0.f;
        l_part[i] = 0.f;
    }

    const bf16* kfb = kpk + (size_t)b * 128 * 16 * 512;
    const bf16* vfb = vpk + (size_t)b * 64 * 4 * 8 * 512;

    // prime the K prefetch for s0 = 0
    bf16x8 kpre[8];
    {
        const bf16* kf0 = kfb + ((size_t)sh * 16 * 64 + lane) * 8;
        #pragma unroll
        for (int c = 0; c < 8; ++c) kpre[c] = *(const bf16x8*)(kf0 + (size_t)c * 512);
    }

    for (int s0 = 0; s0 < T_LEN; s0 += 64) {
        const int buf = (s0 >> 6) & 1;
        const bf16* kf  = kfb + (((size_t)((s0 >> 5) + sh)) * 16 * 64 + lane) * 8;
        const bf16* kfn = kfb + (((size_t)(((s0 + 64) >> 5) + sh)) * 16 * 64 + lane) * 8;

        // second half of current iter's K-frags
        bf16x8 kc2[8];
        #pragma unroll
        for (int c = 0; c < 8; ++c) kc2[c] = *(const bf16x8*)(kf + (size_t)(8 + c) * 512);

        // QK: S quadrant [t=rg*32..][s=s0+sh*32..], K=256.
        // TWO independent 8-MFMA chains (half the serial latency), then add.
        f32x16 accsA, accsB;
        #pragma unroll
        for (int i = 0; i < 16; ++i) { accsA[i] = 0.f; accsB[i] = 0.f; }
        #pragma unroll
        for (int c = 0; c < 8; ++c) {
            accsA = MFMA32(qf[c],     kpre[c], accsA);
            accsB = MFMA32(qf[8 + c], kc2[c],  accsB);
        }
        f32x16 accs;
        #pragma unroll
        for (int i = 0; i < 16; ++i) accs[i] = accsA[i] + accsB[i];

        // V-frags for this iter, then next-iter K prefetch — both fly through
        // exp/Ps/barrier/PV.
        const bf16* vf = vfb + (((size_t)(s0 >> 6) * 4) * 8 + wave * 2) * 512 + (size_t)lane * 8;
        bf16x8 bv[8];
        #pragma unroll
        for (int ks = 0; ks < 4; ++ks) {
            bv[ks * 2]     = *(const bf16x8*)(vf + (size_t)ks * 8 * 512);
            bv[ks * 2 + 1] = *(const bf16x8*)(vf + (size_t)(ks * 8 + 1) * 512);
        }
        #pragma unroll
        for (int c = 0; c < 8; ++c) kpre[c] = *(const bf16x8*)(kfn + (size_t)c * 512);

        // P = exp(S); l accumulated on the bf16-rounded value
        #pragma unroll
        for (int r = 0; r < 16; ++r) {
            float p = __expf(accs[r]);
            bf16 pb = (bf16)p;
            l_part[r] += (float)pb;
            int row = rg * 32 + (r & 3) + 8 * (r >> 2) + 4 * half;
            Ps[buf][row][sh * 32 + l31] = pb;
        }

        BARRIER_LGKM();   // Ps[buf] visible; global loads stay outstanding

        // PV: O[0..63][wave*64..+64) += P @ V
        #pragma unroll
        for (int ks = 0; ks < 4; ++ks) {
            bf16x8 ap0 = *(const bf16x8*)&Ps[buf][l31][ks * 16 + half * 8];
            bf16x8 ap1 = *(const bf16x8*)&Ps[buf][32 + l31][ks * 16 + half * 8];
            acc_o[0][0] = MFMA32(ap0, bv[ks * 2],     acc_o[0][0]);
            acc_o[0][1] = MFMA32(ap0, bv[ks * 2 + 1], acc_o[0][1]);
            acc_o[1][0] = MFMA32(ap1, bv[ks * 2],     acc_o[1][0]);
            acc_o[1][1] = MFMA32(ap1, bv[ks * 2 + 1], acc_o[1][1]);
        }
    }

    // ---- l reduction: across 32 cols (shuffle), then across sh waves (LDS) ----
    #pragma unroll
    for (int r = 0; r < 16; ++r) {
        float v = l_part[r];
        v += __shfl_xor(v, 1, 64);
        v += __shfl_xor(v, 2, 64);
        v += __shfl_xor(v, 4, 64);
        v += __shfl_xor(v, 8, 64);
        v += __shfl_xor(v, 16, 64);
        l_part[r] = v;
    }
    if (l31 == 0) {
        #pragma unroll
        for (int r = 0; r < 16; ++r) {
            const int row = rg * 32 + (r & 3) + 8 * (r >> 2) + 4 * half;
            l_red[sh][row] = l_part[r];
        }
    }
    __syncthreads();

    // ---- stage normalized O-tile in LDS (bf16 — same rounding as before) ----
    #pragma unroll
    for (int rt = 0; rt < 2; ++rt) {
        #pragma unroll
        for (int r = 0; r < 16; ++r) {
            const int row = rt * 32 + (r & 3) + 8 * (r >> 2) + 4 * half;
            const float linv = 1.0f / (l_red[0][row] + l_red[1][row]);
            At[row][wave * 64 + l31]      = (bf16)(acc_o[rt][0][r] * linv);
            At[row][wave * 64 + 32 + l31] = (bf16)(acc_o[rt][1][r] * linv);
        }
    }
    __syncthreads();

    // ---- fused out_proj: out-rows t0..t0+63 (batch b) = At @ W_out + b_out ----
    {
        const int l15 = lane & 15, quad = lane >> 4;
        const int arow = wave * 16 + l15;
        bf16x8 af[8];
        #pragma unroll
        for (int kt = 0; kt < 8; ++kt)
            af[kt] = *(const bf16x8*)&At[arow][quad * 8 + kt * 32];

        for (int ch = 0; ch < 4; ++ch) {
            f32x4 acc[4];
            #pragma unroll
            for (int i = 0; i < 4; ++i)
                for (int r = 0; r < 4; ++r) acc[i][r] = 0.f;
            #pragma unroll
            for (int kt = 0; kt < 8; ++kt) {
                #pragma unroll
                for (int nt = 0; nt < 4; ++nt) {
                    bf16x8 bb = *(const bf16x8*)&wop[((((size_t)ch * 8 + kt) * 4 + nt) * 64 + lane) * 8];
                    acc[nt] = MFMA16(af[kt], bb, acc[nt]);
                }
            }
            #pragma unroll
            for (int nt = 0; nt < 4; ++nt) {
                const int n = ch * 64 + nt * 16 + l15;
                const float bias = b_out[n];
                #pragma unroll
                for (int r = 0; r < 4; ++r) {
                    const int t = t0 + wave * 16 + quad * 4 + r;
                    out[((size_t)t * BATCH + b) * O_DIM + n] = acc[nt][r] + bias;
                }
            }
        }
    }
}

extern "C" void kernel_launch(void* const* d_in, const int* in_sizes, int n_in,
                              void* d_out, int out_size, void* d_ws, size_t ws_size,
                              hipStream_t stream) {
    const float* query = (const float*)d_in[0];
    const float* W_kqv = (const float*)d_in[1];
    const float* b_kqv = (const float*)d_in[2];
    const float* W_out = (const float*)d_in[3];
    const float* b_out = (const float*)d_in[4];
    float* out = (float*)d_out;

    const size_t BUF = (size_t)BATCH * T_LEN * P_DIM;
    bf16* qb   = (bf16*)d_ws;
    bf16* kpk  = qb + BUF;       // fragment-packed K
    bf16* vpk  = kpk + BUF;      // fragment-packed V
    bf16* scr  = vpk + BUF;      // scratch region (weights)
    bf16* wkp  = scr;            // packed W_kqv: 196,608 bf16
    bf16* wop  = scr + 262144;   // packed W_out: 65,536 bf16 (disjoint)

    wpack_all_kernel<<<128, 256, 0, stream>>>(W_kqv, W_out, wkp, wop);
    qkv_proj_kernel<<<512, 256, 0, stream>>>(query, wkp, b_kqv, qb, kpk, vpk);
    flash_attn_kernel<<<512, 256, 0, stream>>>(qb, kpk, vpk, wop, b_out, out);
}

// Round 11
// 270.238 us; speedup vs baseline: 1.0174x; 1.0174x over previous
//
#include <hip/hip_runtime.h>
#include <hip/hip_bf16.h>

#define T_LEN 4096
#define BATCH 8
#define D_DIM 256
#define P_DIM 256
#define O_DIM 256
#define N3    768

typedef __bf16 bf16;
typedef __attribute__((ext_vector_type(8))) __bf16 bf16x8;
typedef __attribute__((ext_vector_type(4))) __bf16 bf16x4;
typedef __attribute__((ext_vector_type(4))) float f32x4;
typedef __attribute__((ext_vector_type(16))) float f32x16;

#define MFMA16(a, b, c) __builtin_amdgcn_mfma_f32_16x16x32_bf16(a, b, c, 0, 0, 0)
#define MFMA32(a, b, c) __builtin_amdgcn_mfma_f32_32x32x16_bf16(a, b, c, 0, 0, 0)

#define LDS_P 72  // P rows: 144B stride

// lgkm-only barrier: drains LDS ops but leaves global/gload_lds in flight.
#define BARRIER_LGKM() __asm__ __volatile__("s_waitcnt lgkmcnt(0)\n\ts_barrier" ::: "memory")
// vmcnt(N)-counted barrier: wait for a staged LDS tile whose loads are the N
// newest outstanding vmem ops.
#define BARRIER_VM(N) __asm__ __volatile__("s_waitcnt vmcnt(" #N ")\n\ts_barrier" ::: "memory")

typedef __attribute__((address_space(1))) const unsigned int g_u32;
typedef __attribute__((address_space(3))) unsigned int l_u32;
// async global->LDS, 16B per lane; LDS dest is wave-uniform base + lane*16.
#define GLD16(gp, lp) __builtin_amdgcn_global_load_lds((g_u32*)(gp), (l_u32*)(lp), 16, 0, 0)

// ---------------------------------------------------------------------------
// K0: fragment-major weight pack (proven), both weights in ONE dispatch.
// ---------------------------------------------------------------------------
__device__ __forceinline__ void wpack_body(
    const float* __restrict__ src, bf16* __restrict__ dst, int ncols, int g)
{
    const int lane = g & 63;
    const int idx = g >> 6;
    const int nt = idx & 3, kt = (idx >> 2) & 7, ch = idx >> 5;
    const int n = ch * 64 + nt * 16 + (lane & 15);
    const int kb = kt * 32 + (lane >> 4) * 8;
    bf16x8 pk;
    #pragma unroll
    for (int j = 0; j < 8; ++j) pk[j] = (bf16)src[(size_t)(kb + j) * ncols + n];
    *(bf16x8*)&dst[(size_t)g * 8] = pk;
}

__global__ __launch_bounds__(256) void wpack_all_kernel(
    const float* __restrict__ W_kqv, const float* __restrict__ W_out,
    bf16* __restrict__ wkp, bf16* __restrict__ wop)
{
    const int bid = blockIdx.x;
    if (bid < 96) {
        wpack_body(W_kqv, wkp, N3, bid * 256 + threadIdx.x);
    } else {
        wpack_body(W_out, wop, O_DIM, (bid - 96) * 256 + threadIdx.x);
    }
}

// ---------------------------------------------------------------------------
// K1 v6 (R6 config — proven best by R10 isolation: staged beats direct ~5 µs):
// LDS-staged weights + Tt vector stores.
// ---------------------------------------------------------------------------
__global__ __launch_bounds__(256) void qkv_proj_kernel(
    const float* __restrict__ query, const bf16* __restrict__ wkp,
    const float* __restrict__ b_kqv,
    bf16* __restrict__ qb, bf16* __restrict__ kpk, bf16* __restrict__ vpk)
{
    __shared__ __align__(16) bf16 Tt[64][72];     // 9 KB transpose tile
    __shared__ __align__(16) bf16 Wb[2][16384];   // 2 x 32KB ch-tile
    const int m0 = blockIdx.x * 64;
    const int t0g = m0 >> 3;
    const int tid = threadIdx.x;
    const int lane = tid & 63, wave = tid >> 6, l15 = lane & 15, quad = lane >> 4;
    const int arow = wave * 16 + l15;

#define STAGE_W(CH, NB)                                                       \
    {                                                                         \
        const bf16* gsrc = wkp + (size_t)(CH) * 16384;                        \
        _Pragma("unroll")                                                     \
        for (int j = 0; j < 8; ++j)                                           \
            GLD16(gsrc + ((size_t)j * 256 + tid) * 8,                         \
                  &Wb[NB][(j * 256 + wave * 64) * 8]);                        \
    }

    STAGE_W(0, 0);   // prime tile 0

    bf16x8 af[8];
    {
        const float* qsrc = query + (size_t)(m0 + arow) * D_DIM + quad * 8;
        #pragma unroll
        for (int kt = 0; kt < 8; ++kt) {
            float4 f0 = *(const float4*)(qsrc + kt * 32);
            float4 f1 = *(const float4*)(qsrc + kt * 32 + 4);
            af[kt] = bf16x8{(bf16)f0.x, (bf16)f0.y, (bf16)f0.z, (bf16)f0.w,
                            (bf16)f1.x, (bf16)f1.y, (bf16)f1.z, (bf16)f1.w};
        }
    }

    for (int ch = 0; ch < 12; ++ch) {
        const int buf = ch & 1;
        if (ch < 11) {
            STAGE_W(ch + 1, buf ^ 1);   // 8 newest vmem ops
            BARRIER_VM(8);              // tile(ch) landed in Wb[buf], all waves
        } else {
            BARRIER_VM(0);
        }

        f32x4 acc[4];
        #pragma unroll
        for (int i = 0; i < 4; ++i)
            for (int r = 0; r < 4; ++r) acc[i][r] = 0.f;
        #pragma unroll
        for (int kt = 0; kt < 8; ++kt) {
            #pragma unroll
            for (int nt = 0; nt < 4; ++nt) {
                bf16x8 bb = *(const bf16x8*)&Wb[buf][((kt * 4 + nt) * 64 + lane) * 8];
                acc[nt] = MFMA16(af[kt], bb, acc[nt]);
            }
        }

        BARRIER_LGKM();   // Tt free (previous iter's readers retired)

        if (ch < 8) {
            // q/k: stage m-major (scaled q), bit-identical rounding
            const float scale = (ch < 4) ? 0.0625f : 1.0f;
            #pragma unroll
            for (int nt = 0; nt < 4; ++nt) {
                const int c = ch * 64 + nt * 16 + l15;
                const float bias = b_kqv[c];
                #pragma unroll
                for (int r = 0; r < 4; ++r)
                    Tt[wave * 16 + quad * 4 + r][nt * 16 + l15]
                        = (bf16)((acc[nt][r] + bias) * scale);
            }
            BARRIER_LGKM();   // Tt visible
            if (ch < 4) {
                #pragma unroll
                for (int uu = 0; uu < 2; ++uu) {
                    const int u = tid * 2 + uu;
                    const int row = u >> 3, cl = u & 7;
                    bf16x8 pk = *(const bf16x8*)&Tt[row][cl * 8];
                    const int m = m0 + row, t = m >> 3, bi = m & 7;
                    *(bf16x8*)&qb[((size_t)bi * T_LEN + t) * P_DIM + ch * 64 + cl * 8] = pk;
                }
            } else {
                #pragma unroll
                for (int uu = 0; uu < 2; ++uu) {
                    const int u = tid * 2 + uu;
                    const int cl = u >> 6, bi = (u >> 3) & 7, idx = u & 7;
                    const int row = idx * 8 + bi;
                    bf16x8 pk = *(const bf16x8*)&Tt[row][cl * 8];
                    const int t = t0g + idx;
                    const int st32 = t >> 5, n31 = t & 31;
                    const int c16 = (ch - 4) * 4 + (cl >> 1), halfk = cl & 1;
                    *(bf16x8*)&kpk[(size_t)((((bi * 128 + st32) * 16 + c16) * 64
                                             + halfk * 32 + n31) * 8)] = pk;
                }
            }
        } else {
            // V: stage c-major (fragment pack needs m-gather) — proven path
            #pragma unroll
            for (int nt = 0; nt < 4; ++nt) {
                const int c = ch * 64 + nt * 16 + l15;
                const float bias = b_kqv[c];
                #pragma unroll
                for (int r = 0; r < 4; ++r)
                    Tt[nt * 16 + l15][wave * 16 + quad * 4 + r] = (bf16)(acc[nt][r] + bias);
            }
            BARRIER_LGKM();   // Tt visible
            const int s64 = t0g >> 6, ks = (t0g >> 4) & 3, halfv = (t0g >> 3) & 1;
            #pragma unroll
            for (int uu = 0; uu < 2; ++uu) {
                const int u = tid * 2 + uu;
                const int cl = u >> 3, bi = u & 7;
                bf16x8 pk;
                #pragma unroll
                for (int j = 0; j < 8; ++j) pk[j] = Tt[cl][j * 8 + bi];
                const int cc = (ch - 8) * 64 + cl;
                const int ptG = cc >> 5, n31 = cc & 31;
                *(bf16x8*)&vpk[((((size_t)bi * 64 + s64) * 4 + ks) * 8 + ptG) * 512
                               + (size_t)(halfv * 32 + n31) * 8] = pk;
            }
        }
    }
#undef STAGE_W
}

// ---------------------------------------------------------------------------
// K2 v10: flash attention + fused out_proj. Changes vs R9:
//  - PHASE-STAGGERED s-sweep: block phase p starts at s = p*2048, wraps mod
//    4096. R10 accounting: L2(3400) + MFMA(2050) + VALU(1500) cyc/CU-iter sum
//    to the 6400-cyc wall -> the 2 co-resident blocks are phase-LOCKED (zero
//    overlap). Opposite phases put one block's MFMA cluster under the other's
//    exp/load/barrier hole. KV = 4MB/XCD = exactly L2 -> residency is
//    phase-independent. Only the f32 summation ORDER of l/O rotates (P is
//    bf16-rounded per-element before summing) -> ~1e-7 rel perturbation.
//  - Phase bit ((bid>>8)^(bid>>3)^bid)&1 differs across a co-resident pair
//    for pair-mappings (i,i+256), (i,i+8), (2i,2i+1). Wrong mapping => null.
//  - QK two-chain split kept (R9: verified -4 µs, no spills).
// ---------------------------------------------------------------------------
__global__ __launch_bounds__(256, 2) void flash_attn_kernel(
    const bf16* __restrict__ qb, const bf16* __restrict__ kpk,
    const bf16* __restrict__ vpk, const bf16* __restrict__ wop,
    const float* __restrict__ b_out, float* __restrict__ out)
{
    __shared__ __align__(16) bf16 Ps[2][64][LDS_P];   // 18.4 KB
    __shared__ float l_red[2][64];                    // [sh][row]
    __shared__ __align__(16) bf16 At[64][264];        // 33.8 KB

    const int bid = blockIdx.x;
    const int b = bid & 7;                 // bid%8 == XCD: 4 MB KV per XCD L2
    const int t0 = (bid >> 3) * 64;
    const int tid = threadIdx.x;
    const int lane = tid & 63, wave = tid >> 6;
    const int l31 = lane & 31, half = lane >> 5;
    const int rg = wave & 1, sh = wave >> 1;
    const int s_start = (((bid >> 8) ^ (bid >> 3) ^ bid) & 1) * 2048;

    // Q A-frags (row=lane&31, k=half*8+j), rows rg*32..+32 — proven layout
    bf16x8 qf[16];
    {
        const bf16* qrow = qb + ((size_t)b * T_LEN + t0 + rg * 32 + l31) * P_DIM + half * 8;
        #pragma unroll
        for (int kt = 0; kt < 16; ++kt) qf[kt] = *(const bf16x8*)(qrow + kt * 16);
    }

    f32x16 acc_o[2][2];   // [t-tile][p-tile]
    float l_part[16];
    #pragma unroll
    for (int i = 0; i < 16; ++i) {
        acc_o[0][0][i] = 0.f; acc_o[0][1][i] = 0.f;
        acc_o[1][0][i] = 0.f; acc_o[1][1][i] = 0.f;
        l_part[i] = 0.f;
    }

    const bf16* kfb = kpk + (size_t)b * 128 * 16 * 512;
    const bf16* vfb = vpk + (size_t)b * 64 * 4 * 8 * 512;

    // prime the K prefetch for the first s-tile (s = s_start)
    bf16x8 kpre[8];
    {
        const bf16* kf0 = kfb + (((size_t)((s_start >> 5) + sh)) * 16 * 64 + lane) * 8;
        #pragma unroll
        for (int c = 0; c < 8; ++c) kpre[c] = *(const bf16x8*)(kf0 + (size_t)c * 512);
    }

    for (int it = 0; it < 64; ++it) {
        const int s0  = (s_start + it * 64) & (T_LEN - 1);
        const int s0n = (s_start + (it + 1) * 64) & (T_LEN - 1);
        const int buf = it & 1;
        const bf16* kf  = kfb + (((size_t)((s0 >> 5) + sh)) * 16 * 64 + lane) * 8;
        const bf16* kfn = kfb + (((size_t)((s0n >> 5) + sh)) * 16 * 64 + lane) * 8;

        // second half of current iter's K-frags
        bf16x8 kc2[8];
        #pragma unroll
        for (int c = 0; c < 8; ++c) kc2[c] = *(const bf16x8*)(kf + (size_t)(8 + c) * 512);

        // QK: S quadrant [t=rg*32..][s=s0+sh*32..], K=256.
        // TWO independent 8-MFMA chains (half the serial latency), then add.
        f32x16 accsA, accsB;
        #pragma unroll
        for (int i = 0; i < 16; ++i) { accsA[i] = 0.f; accsB[i] = 0.f; }
        #pragma unroll
        for (int c = 0; c < 8; ++c) {
            accsA = MFMA32(qf[c],     kpre[c], accsA);
            accsB = MFMA32(qf[8 + c], kc2[c],  accsB);
        }
        f32x16 accs;
        #pragma unroll
        for (int i = 0; i < 16; ++i) accs[i] = accsA[i] + accsB[i];

        // V-frags for this iter, then next-iter K prefetch — both fly through
        // exp/Ps/barrier/PV.
        const bf16* vf = vfb + (((size_t)(s0 >> 6) * 4) * 8 + wave * 2) * 512 + (size_t)lane * 8;
        bf16x8 bv[8];
        #pragma unroll
        for (int ks = 0; ks < 4; ++ks) {
            bv[ks * 2]     = *(const bf16x8*)(vf + (size_t)ks * 8 * 512);
            bv[ks * 2 + 1] = *(const bf16x8*)(vf + (size_t)(ks * 8 + 1) * 512);
        }
        #pragma unroll
        for (int c = 0; c < 8; ++c) kpre[c] = *(const bf16x8*)(kfn + (size_t)c * 512);

        // P = exp(S); l accumulated on the bf16-rounded value
        #pragma unroll
        for (int r = 0; r < 16; ++r) {
            float p = __expf(accs[r]);
            bf16 pb = (bf16)p;
            l_part[r] += (float)pb;
            int row = rg * 32 + (r & 3) + 8 * (r >> 2) + 4 * half;
            Ps[buf][row][sh * 32 + l31] = pb;
        }

        BARRIER_LGKM();   // Ps[buf] visible; global loads stay outstanding

        // PV: O[0..63][wave*64..+64) += P @ V
        #pragma unroll
        for (int ks = 0; ks < 4; ++ks) {
            bf16x8 ap0 = *(const bf16x8*)&Ps[buf][l31][ks * 16 + half * 8];
            bf16x8 ap1 = *(const bf16x8*)&Ps[buf][32 + l31][ks * 16 + half * 8];
            acc_o[0][0] = MFMA32(ap0, bv[ks * 2],     acc_o[0][0]);
            acc_o[0][1] = MFMA32(ap0, bv[ks * 2 + 1], acc_o[0][1]);
            acc_o[1][0] = MFMA32(ap1, bv[ks * 2],     acc_o[1][0]);
            acc_o[1][1] = MFMA32(ap1, bv[ks * 2 + 1], acc_o[1][1]);
        }
    }

    // ---- l reduction: across 32 cols (shuffle), then across sh waves (LDS) ----
    #pragma unroll
    for (int r = 0; r < 16; ++r) {
        float v = l_part[r];
        v += __shfl_xor(v, 1, 64);
        v += __shfl_xor(v, 2, 64);
        v += __shfl_xor(v, 4, 64);
        v += __shfl_xor(v, 8, 64);
        v += __shfl_xor(v, 16, 64);
        l_part[r] = v;
    }
    if (l31 == 0) {
        #pragma unroll
        for (int r = 0; r < 16; ++r) {
            const int row = rg * 32 + (r & 3) + 8 * (r >> 2) + 4 * half;
            l_red[sh][row] = l_part[r];
        }
    }
    __syncthreads();

    // ---- stage normalized O-tile in LDS (bf16 — same rounding as before) ----
    #pragma unroll
    for (int rt = 0; rt < 2; ++rt) {
        #pragma unroll
        for (int r = 0; r < 16; ++r) {
            const int row = rt * 32 + (r & 3) + 8 * (r >> 2) + 4 * half;
            const float linv = 1.0f / (l_red[0][row] + l_red[1][row]);
            At[row][wave * 64 + l31]      = (bf16)(acc_o[rt][0][r] * linv);
            At[row][wave * 64 + 32 + l31] = (bf16)(acc_o[rt][1][r] * linv);
        }
    }
    __syncthreads();

    // ---- fused out_proj: out-rows t0..t0+63 (batch b) = At @ W_out + b_out ----
    {
        const int l15 = lane & 15, quad = lane >> 4;
        const int arow = wave * 16 + l15;
        bf16x8 af[8];
        #pragma unroll
        for (int kt = 0; kt < 8; ++kt)
            af[kt] = *(const bf16x8*)&At[arow][quad * 8 + kt * 32];

        for (int ch = 0; ch < 4; ++ch) {
            f32x4 acc[4];
            #pragma unroll
            for (int i = 0; i < 4; ++i)
                for (int r = 0; r < 4; ++r) acc[i][r] = 0.f;
            #pragma unroll
            for (int kt = 0; kt < 8; ++kt) {
                #pragma unroll
                for (int nt = 0; nt < 4; ++nt) {
                    bf16x8 bb = *(const bf16x8*)&wop[((((size_t)ch * 8 + kt) * 4 + nt) * 64 + lane) * 8];
                    acc[nt] = MFMA16(af[kt], bb, acc[nt]);
                }
            }
            #pragma unroll
            for (int nt = 0; nt < 4; ++nt) {
                const int n = ch * 64 + nt * 16 + l15;
                const float bias = b_out[n];
                #pragma unroll
                for (int r = 0; r < 4; ++r) {
                    const int t = t0 + wave * 16 + quad * 4 + r;
                    out[((size_t)t * BATCH + b) * O_DIM + n] = acc[nt][r] + bias;
                }
            }
        }
    }
}

extern "C" void kernel_launch(void* const* d_in, const int* in_sizes, int n_in,
                              void* d_out, int out_size, void* d_ws, size_t ws_size,
                              hipStream_t stream) {
    const float* query = (const float*)d_in[0];
    const float* W_kqv = (const float*)d_in[1];
    const float* b_kqv = (const float*)d_in[2];
    const float* W_out = (const float*)d_in[3];
    const float* b_out = (const float*)d_in[4];
    float* out = (float*)d_out;

    const size_t BUF = (size_t)BATCH * T_LEN * P_DIM;
    bf16* qb   = (bf16*)d_ws;
    bf16* kpk  = qb + BUF;       // fragment-packed K
    bf16* vpk  = kpk + BUF;      // fragment-packed V
    bf16* scr  = vpk + BUF;      // scratch region (weights)
    bf16* wkp  = scr;            // packed W_kqv: 196,608 bf16
    bf16* wop  = scr + 262144;   // packed W_out: 65,536 bf16 (disjoint)

    wpack_all_kernel<<<128, 256, 0, stream>>>(W_kqv, W_out, wkp, wop);
    qkv_proj_kernel<<<512, 256, 0, stream>>>(query, wkp, b_kqv, qb, kpk, vpk);
    flash_attn_kernel<<<512, 256, 0, stream>>>(qb, kpk, vpk, wop, b_out, out);
}

// Round 12
// 266.631 us; speedup vs baseline: 1.0312x; 1.0135x over previous
//
#include <hip/hip_runtime.h>
#include <hip/hip_bf16.h>

#define T_LEN 4096
#define BATCH 8
#define D_DIM 256
#define P_DIM 256
#define O_DIM 256
#define N3    768

typedef __bf16 bf16;
typedef __attribute__((ext_vector_type(8))) __bf16 bf16x8;
typedef __attribute__((ext_vector_type(4))) __bf16 bf16x4;
typedef __attribute__((ext_vector_type(4))) float f32x4;
typedef __attribute__((ext_vector_type(16))) float f32x16;

#define MFMA16(a, b, c) __builtin_amdgcn_mfma_f32_16x16x32_bf16(a, b, c, 0, 0, 0)
#define MFMA32(a, b, c) __builtin_amdgcn_mfma_f32_32x32x16_bf16(a, b, c, 0, 0, 0)

#define LDS_P 72  // P rows: 144B stride

// lgkm-only barrier: drains LDS ops but leaves global/gload_lds in flight.
#define BARRIER_LGKM() __asm__ __volatile__("s_waitcnt lgkmcnt(0)\n\ts_barrier" ::: "memory")
// vmcnt(N)-counted barrier: wait for a staged LDS tile whose loads are the N
// newest outstanding vmem ops.
#define BARRIER_VM(N) __asm__ __volatile__("s_waitcnt vmcnt(" #N ")\n\ts_barrier" ::: "memory")

typedef __attribute__((address_space(1))) const unsigned int g_u32;
typedef __attribute__((address_space(3))) unsigned int l_u32;
// async global->LDS, 16B per lane; LDS dest is wave-uniform base + lane*16.
#define GLD16(gp, lp) __builtin_amdgcn_global_load_lds((g_u32*)(gp), (l_u32*)(lp), 16, 0, 0)

// ---------------------------------------------------------------------------
// K0: fragment-major weight pack (proven), both weights in ONE dispatch.
// ---------------------------------------------------------------------------
__device__ __forceinline__ void wpack_body(
    const float* __restrict__ src, bf16* __restrict__ dst, int ncols, int g)
{
    const int lane = g & 63;
    const int idx = g >> 6;
    const int nt = idx & 3, kt = (idx >> 2) & 7, ch = idx >> 5;
    const int n = ch * 64 + nt * 16 + (lane & 15);
    const int kb = kt * 32 + (lane >> 4) * 8;
    bf16x8 pk;
    #pragma unroll
    for (int j = 0; j < 8; ++j) pk[j] = (bf16)src[(size_t)(kb + j) * ncols + n];
    *(bf16x8*)&dst[(size_t)g * 8] = pk;
}

__global__ __launch_bounds__(256) void wpack_all_kernel(
    const float* __restrict__ W_kqv, const float* __restrict__ W_out,
    bf16* __restrict__ wkp, bf16* __restrict__ wop)
{
    const int bid = blockIdx.x;
    if (bid < 96) {
        wpack_body(W_kqv, wkp, N3, bid * 256 + threadIdx.x);
    } else {
        wpack_body(W_out, wop, O_DIM, (bid - 96) * 256 + threadIdx.x);
    }
}

// ---------------------------------------------------------------------------
// K1 v6 (best qkv — R10 isolation: staged beats direct by ~5 µs):
// LDS-staged weights (double-buffered, GLD16 + counted vmcnt) + Tt vector
// stores (R6: 8x fewer store instructions). Bit-identical rounding.
// ---------------------------------------------------------------------------
__global__ __launch_bounds__(256) void qkv_proj_kernel(
    const float* __restrict__ query, const bf16* __restrict__ wkp,
    const float* __restrict__ b_kqv,
    bf16* __restrict__ qb, bf16* __restrict__ kpk, bf16* __restrict__ vpk)
{
    __shared__ __align__(16) bf16 Tt[64][72];     // 9 KB transpose tile
    __shared__ __align__(16) bf16 Wb[2][16384];   // 2 x 32KB ch-tile
    const int m0 = blockIdx.x * 64;
    const int t0g = m0 >> 3;
    const int tid = threadIdx.x;
    const int lane = tid & 63, wave = tid >> 6, l15 = lane & 15, quad = lane >> 4;
    const int arow = wave * 16 + l15;

#define STAGE_W(CH, NB)                                                       \
    {                                                                         \
        const bf16* gsrc = wkp + (size_t)(CH) * 16384;                        \
        _Pragma("unroll")                                                     \
        for (int j = 0; j < 8; ++j)                                           \
            GLD16(gsrc + ((size_t)j * 256 + tid) * 8,                         \
                  &Wb[NB][(j * 256 + wave * 64) * 8]);                        \
    }

    STAGE_W(0, 0);   // prime tile 0

    bf16x8 af[8];
    {
        const float* qsrc = query + (size_t)(m0 + arow) * D_DIM + quad * 8;
        #pragma unroll
        for (int kt = 0; kt < 8; ++kt) {
            float4 f0 = *(const float4*)(qsrc + kt * 32);
            float4 f1 = *(const float4*)(qsrc + kt * 32 + 4);
            af[kt] = bf16x8{(bf16)f0.x, (bf16)f0.y, (bf16)f0.z, (bf16)f0.w,
                            (bf16)f1.x, (bf16)f1.y, (bf16)f1.z, (bf16)f1.w};
        }
    }

    for (int ch = 0; ch < 12; ++ch) {
        const int buf = ch & 1;
        if (ch < 11) {
            STAGE_W(ch + 1, buf ^ 1);   // 8 newest vmem ops
            BARRIER_VM(8);              // tile(ch) landed in Wb[buf], all waves
        } else {
            BARRIER_VM(0);
        }

        f32x4 acc[4];
        #pragma unroll
        for (int i = 0; i < 4; ++i)
            for (int r = 0; r < 4; ++r) acc[i][r] = 0.f;
        #pragma unroll
        for (int kt = 0; kt < 8; ++kt) {
            #pragma unroll
            for (int nt = 0; nt < 4; ++nt) {
                bf16x8 bb = *(const bf16x8*)&Wb[buf][((kt * 4 + nt) * 64 + lane) * 8];
                acc[nt] = MFMA16(af[kt], bb, acc[nt]);
            }
        }

        BARRIER_LGKM();   // Tt free (previous iter's readers retired)

        if (ch < 8) {
            // q/k: stage m-major (scaled q), bit-identical rounding
            const float scale = (ch < 4) ? 0.0625f : 1.0f;
            #pragma unroll
            for (int nt = 0; nt < 4; ++nt) {
                const int c = ch * 64 + nt * 16 + l15;
                const float bias = b_kqv[c];
                #pragma unroll
                for (int r = 0; r < 4; ++r)
                    Tt[wave * 16 + quad * 4 + r][nt * 16 + l15]
                        = (bf16)((acc[nt][r] + bias) * scale);
            }
            BARRIER_LGKM();   // Tt visible
            if (ch < 4) {
                #pragma unroll
                for (int uu = 0; uu < 2; ++uu) {
                    const int u = tid * 2 + uu;
                    const int row = u >> 3, cl = u & 7;
                    bf16x8 pk = *(const bf16x8*)&Tt[row][cl * 8];
                    const int m = m0 + row, t = m >> 3, bi = m & 7;
                    *(bf16x8*)&qb[((size_t)bi * T_LEN + t) * P_DIM + ch * 64 + cl * 8] = pk;
                }
            } else {
                #pragma unroll
                for (int uu = 0; uu < 2; ++uu) {
                    const int u = tid * 2 + uu;
                    const int cl = u >> 6, bi = (u >> 3) & 7, idx = u & 7;
                    const int row = idx * 8 + bi;
                    bf16x8 pk = *(const bf16x8*)&Tt[row][cl * 8];
                    const int t = t0g + idx;
                    const int st32 = t >> 5, n31 = t & 31;
                    const int c16 = (ch - 4) * 4 + (cl >> 1), halfk = cl & 1;
                    *(bf16x8*)&kpk[(size_t)((((bi * 128 + st32) * 16 + c16) * 64
                                             + halfk * 32 + n31) * 8)] = pk;
                }
            }
        } else {
            // V: stage c-major (fragment pack needs m-gather) — proven path
            #pragma unroll
            for (int nt = 0; nt < 4; ++nt) {
                const int c = ch * 64 + nt * 16 + l15;
                const float bias = b_kqv[c];
                #pragma unroll
                for (int r = 0; r < 4; ++r)
                    Tt[nt * 16 + l15][wave * 16 + quad * 4 + r] = (bf16)(acc[nt][r] + bias);
            }
            BARRIER_LGKM();   // Tt visible
            const int s64 = t0g >> 6, ks = (t0g >> 4) & 3, halfv = (t0g >> 3) & 1;
            #pragma unroll
            for (int uu = 0; uu < 2; ++uu) {
                const int u = tid * 2 + uu;
                const int cl = u >> 3, bi = u & 7;
                bf16x8 pk;
                #pragma unroll
                for (int j = 0; j < 8; ++j) pk[j] = Tt[cl][j * 8 + bi];
                const int cc = (ch - 8) * 64 + cl;
                const int ptG = cc >> 5, n31 = cc & 31;
                *(bf16x8*)&vpk[((((size_t)bi * 64 + s64) * 4 + ks) * 8 + ptG) * 512
                               + (size_t)(halfv * 32 + n31) * 8] = pk;
            }
        }
    }
#undef STAGE_W
}

// ---------------------------------------------------------------------------
// K2 v9 (best flash — R9: 171.1 µs verified, no spills): flash attention +
// fused out_proj epilogue; QK as two independent 8-MFMA chains.
// Phase-stagger removed (R11: +3 µs, +17% FETCH — broke L3 locality).
// ---------------------------------------------------------------------------
__global__ __launch_bounds__(256, 2) void flash_attn_kernel(
    const bf16* __restrict__ qb, const bf16* __restrict__ kpk,
    const bf16* __restrict__ vpk, const bf16* __restrict__ wop,
    const float* __restrict__ b_out, float* __restrict__ out)
{
    __shared__ __align__(16) bf16 Ps[2][64][LDS_P];   // 18.4 KB
    __shared__ float l_red[2][64];                    // [sh][row]
    __shared__ __align__(16) bf16 At[64][264];        // 33.8 KB

    const int bid = blockIdx.x;
    const int b = bid & 7;                 // bid%8 == XCD: 4 MB KV per XCD L2
    const int t0 = (bid >> 3) * 64;
    const int tid = threadIdx.x;
    const int lane = tid & 63, wave = tid >> 6;
    const int l31 = lane & 31, half = lane >> 5;
    const int rg = wave & 1, sh = wave >> 1;

    // Q A-frags (row=lane&31, k=half*8+j), rows rg*32..+32 — proven layout
    bf16x8 qf[16];
    {
        const bf16* qrow = qb + ((size_t)b * T_LEN + t0 + rg * 32 + l31) * P_DIM + half * 8;
        #pragma unroll
        for (int kt = 0; kt < 16; ++kt) qf[kt] = *(const bf16x8*)(qrow + kt * 16);
    }

    f32x16 acc_o[2][2];   // [t-tile][p-tile]
    float l_part[16];
    #pragma unroll
    for (int i = 0; i < 16; ++i) {
        acc_o[0][0][i] = 0.f; acc_o[0][1][i] = 0.f;
        acc_o[1][0][i] = 0.f; acc_o[1][1][i] = 0.f;
        l_part[i] = 0.f;
    }

    const bf16* kfb = kpk + (size_t)b * 128 * 16 * 512;
    const bf16* vfb = vpk + (size_t)b * 64 * 4 * 8 * 512;

    // prime the K prefetch for s0 = 0
    bf16x8 kpre[8];
    {
        const bf16* kf0 = kfb + ((size_t)sh * 16 * 64 + lane) * 8;
        #pragma unroll
        for (int c = 0; c < 8; ++c) kpre[c] = *(const bf16x8*)(kf0 + (size_t)c * 512);
    }

    for (int s0 = 0; s0 < T_LEN; s0 += 64) {
        const int buf = (s0 >> 6) & 1;
        const bf16* kf  = kfb + (((size_t)((s0 >> 5) + sh)) * 16 * 64 + lane) * 8;
        const bf16* kfn = kfb + (((size_t)(((s0 + 64) >> 5) + sh)) * 16 * 64 + lane) * 8;

        // second half of current iter's K-frags
        bf16x8 kc2[8];
        #pragma unroll
        for (int c = 0; c < 8; ++c) kc2[c] = *(const bf16x8*)(kf + (size_t)(8 + c) * 512);

        // QK: S quadrant [t=rg*32..][s=s0+sh*32..], K=256.
        // TWO independent 8-MFMA chains (half the serial latency), then add.
        f32x16 accsA, accsB;
        #pragma unroll
        for (int i = 0; i < 16; ++i) { accsA[i] = 0.f; accsB[i] = 0.f; }
        #pragma unroll
        for (int c = 0; c < 8; ++c) {
            accsA = MFMA32(qf[c],     kpre[c], accsA);
            accsB = MFMA32(qf[8 + c], kc2[c],  accsB);
        }
        f32x16 accs;
        #pragma unroll
        for (int i = 0; i < 16; ++i) accs[i] = accsA[i] + accsB[i];

        // V-frags for this iter, then next-iter K prefetch — both fly through
        // exp/Ps/barrier/PV.
        const bf16* vf = vfb + (((size_t)(s0 >> 6) * 4) * 8 + wave * 2) * 512 + (size_t)lane * 8;
        bf16x8 bv[8];
        #pragma unroll
        for (int ks = 0; ks < 4; ++ks) {
            bv[ks * 2]     = *(const bf16x8*)(vf + (size_t)ks * 8 * 512);
            bv[ks * 2 + 1] = *(const bf16x8*)(vf + (size_t)(ks * 8 + 1) * 512);
        }
        #pragma unroll
        for (int c = 0; c < 8; ++c) kpre[c] = *(const bf16x8*)(kfn + (size_t)c * 512);

        // P = exp(S); l accumulated on the bf16-rounded value
        #pragma unroll
        for (int r = 0; r < 16; ++r) {
            float p = __expf(accs[r]);
            bf16 pb = (bf16)p;
            l_part[r] += (float)pb;
            int row = rg * 32 + (r & 3) + 8 * (r >> 2) + 4 * half;
            Ps[buf][row][sh * 32 + l31] = pb;
        }

        BARRIER_LGKM();   // Ps[buf] visible; global loads stay outstanding

        // PV: O[0..63][wave*64..+64) += P @ V
        #pragma unroll
        for (int ks = 0; ks < 4; ++ks) {
            bf16x8 ap0 = *(const bf16x8*)&Ps[buf][l31][ks * 16 + half * 8];
            bf16x8 ap1 = *(const bf16x8*)&Ps[buf][32 + l31][ks * 16 + half * 8];
            acc_o[0][0] = MFMA32(ap0, bv[ks * 2],     acc_o[0][0]);
            acc_o[0][1] = MFMA32(ap0, bv[ks * 2 + 1], acc_o[0][1]);
            acc_o[1][0] = MFMA32(ap1, bv[ks * 2],     acc_o[1][0]);
            acc_o[1][1] = MFMA32(ap1, bv[ks * 2 + 1], acc_o[1][1]);
        }
    }

    // ---- l reduction: across 32 cols (shuffle), then across sh waves (LDS) ----
    #pragma unroll
    for (int r = 0; r < 16; ++r) {
        float v = l_part[r];
        v += __shfl_xor(v, 1, 64);
        v += __shfl_xor(v, 2, 64);
        v += __shfl_xor(v, 4, 64);
        v += __shfl_xor(v, 8, 64);
        v += __shfl_xor(v, 16, 64);
        l_part[r] = v;
    }
    if (l31 == 0) {
        #pragma unroll
        for (int r = 0; r < 16; ++r) {
            const int row = rg * 32 + (r & 3) + 8 * (r >> 2) + 4 * half;
            l_red[sh][row] = l_part[r];
        }
    }
    __syncthreads();

    // ---- stage normalized O-tile in LDS (bf16 — same rounding as before) ----
    #pragma unroll
    for (int rt = 0; rt < 2; ++rt) {
        #pragma unroll
        for (int r = 0; r < 16; ++r) {
            const int row = rt * 32 + (r & 3) + 8 * (r >> 2) + 4 * half;
            const float linv = 1.0f / (l_red[0][row] + l_red[1][row]);
            At[row][wave * 64 + l31]      = (bf16)(acc_o[rt][0][r] * linv);
            At[row][wave * 64 + 32 + l31] = (bf16)(acc_o[rt][1][r] * linv);
        }
    }
    __syncthreads();

    // ---- fused out_proj: out-rows t0..t0+63 (batch b) = At @ W_out + b_out ----
    {
        const int l15 = lane & 15, quad = lane >> 4;
        const int arow = wave * 16 + l15;
        bf16x8 af[8];
        #pragma unroll
        for (int kt = 0; kt < 8; ++kt)
            af[kt] = *(const bf16x8*)&At[arow][quad * 8 + kt * 32];

        for (int ch = 0; ch < 4; ++ch) {
            f32x4 acc[4];
            #pragma unroll
            for (int i = 0; i < 4; ++i)
                for (int r = 0; r < 4; ++r) acc[i][r] = 0.f;
            #pragma unroll
            for (int kt = 0; kt < 8; ++kt) {
                #pragma unroll
                for (int nt = 0; nt < 4; ++nt) {
                    bf16x8 bb = *(const bf16x8*)&wop[((((size_t)ch * 8 + kt) * 4 + nt) * 64 + lane) * 8];
                    acc[nt] = MFMA16(af[kt], bb, acc[nt]);
                }
            }
            #pragma unroll
            for (int nt = 0; nt < 4; ++nt) {
                const int n = ch * 64 + nt * 16 + l15;
                const float bias = b_out[n];
                #pragma unroll
                for (int r = 0; r < 4; ++r) {
                    const int t = t0 + wave * 16 + quad * 4 + r;
                    out[((size_t)t * BATCH + b) * O_DIM + n] = acc[nt][r] + bias;
                }
            }
        }
    }
}

extern "C" void kernel_launch(void* const* d_in, const int* in_sizes, int n_in,
                              void* d_out, int out_size, void* d_ws, size_t ws_size,
                              hipStream_t stream) {
    const float* query = (const float*)d_in[0];
    const float* W_kqv = (const float*)d_in[1];
    const float* b_kqv = (const float*)d_in[2];
    const float* W_out = (const float*)d_in[3];
    const float* b_out = (const float*)d_in[4];
    float* out = (float*)d_out;

    const size_t BUF = (size_t)BATCH * T_LEN * P_DIM;
    bf16* qb   = (bf16*)d_ws;
    bf16* kpk  = qb + BUF;       // fragment-packed K
    bf16* vpk  = kpk + BUF;      // fragment-packed V
    bf16* scr  = vpk + BUF;      // scratch region (weights)
    bf16* wkp  = scr;            // packed W_kqv: 196,608 bf16
    bf16* wop  = scr + 262144;   // packed W_out: 65,536 bf16 (disjoint)

    wpack_all_kernel<<<128, 256, 0, stream>>>(W_kqv, W_out, wkp, wop);
    qkv_proj_kernel<<<512, 256, 0, stream>>>(query, wkp, b_kqv, qb, kpk, vpk);
    flash_attn_kernel<<<512, 256, 0, stream>>>(qb, kpk, vpk, wop, b_out, out);
}